// Round 1
// baseline (551.205 us; speedup 1.0000x reference)
//
#include <hip/hip_runtime.h>
#include <cfloat>
#include <math.h>

// Problem constants (z: [16,64,64,256] fp32, codebook: [1024,256] fp32)
#define P_TOT 65536
#define DIM   256
#define KTOT  1024
#define BETA_ 0.25f
#define EPS_  1e-5f

// d_out layout (float32, concatenated in reference return order):
// [0, P*D)            z_q_st
// [P*D + 0]           commitment_loss
// [P*D + 1]           codebook_loss
// [P*D + 2]           cluster_loss
// [P*D + 3]           perplexity
// [P*D + 4, +P)       indices (as float)
#define OUT_LOSS_OFF ((size_t)P_TOT * DIM)
#define OUT_IDX_OFF  (OUT_LOSS_OFF + 4)

// ---------------- prep: e2[k] = sum(codebook[k]^2), zero hist & loss_sum ---
__global__ __launch_bounds__(64) void vq_prep(const float* __restrict__ cb,
                                              float* __restrict__ e2,
                                              unsigned int* __restrict__ hist,
                                              float* __restrict__ loss_sum) {
    const int k = blockIdx.x;
    const int lane = threadIdx.x;
    float4 v = *(const float4*)(cb + (size_t)k * DIM + lane * 4);
    float s = v.x * v.x + v.y * v.y + v.z * v.z + v.w * v.w;
    #pragma unroll
    for (int off = 32; off > 0; off >>= 1) s += __shfl_down(s, off, 64);
    if (lane == 0) e2[k] = s;
    const int gid = k * 64 + lane;
    if (gid < KTOT) hist[gid] = 0u;
    if (gid == KTOT) *loss_sum = 0.0f;
}

// ---------------- z2[p] = sum(z[p]^2), one wave per pixel -------------------
__global__ __launch_bounds__(256) void vq_z2(const float* __restrict__ z,
                                             float* __restrict__ z2) {
    const int lane = threadIdx.x & 63;
    const int wave = threadIdx.x >> 6;
    const int p = blockIdx.x * 4 + wave;
    float4 v = *(const float4*)(z + (size_t)p * DIM + lane * 4);
    float s = v.x * v.x + v.y * v.y + v.z * v.z + v.w * v.w;
    #pragma unroll
    for (int off = 32; off > 0; off >>= 1) s += __shfl_down(s, off, 64);
    if (lane == 0) z2[p] = s;
}

// ---------------- main: tiled fp32 GEMM-argmin + fused epilogue -------------
#define BM 128
#define BN 128
#define BD 32
#define PADM 132   // 128+4: keeps rows 16B-aligned for b128 LDS reads

struct Tiles { float As[BD][PADM]; float Bs[BD][PADM]; };
struct Red   { float d[BM][17]; int i[BM][17]; };

__global__ __launch_bounds__(256) void vq_argmin(
    const float* __restrict__ z, const float* __restrict__ cb,
    const float* __restrict__ z2, const float* __restrict__ e2,
    unsigned int* __restrict__ hist, float* __restrict__ loss_sum,
    float* __restrict__ out)
{
    __shared__ __align__(16) char smraw[sizeof(Tiles)];
    static_assert(sizeof(Red) <= sizeof(Tiles), "red fits in tiles");
    Tiles& T = *reinterpret_cast<Tiles*>(smraw);
    Red&   R = *reinterpret_cast<Red*>(smraw);
    __shared__ int   kwin[BM];
    __shared__ float wred[4];

    const int tid = threadIdx.x;
    const int tx = tid & 15;       // k-column group
    const int ty = tid >> 4;       // pixel-row group
    const int row0 = blockIdx.x * BM;

    float z2r[8];
    #pragma unroll
    for (int r = 0; r < 8; ++r) z2r[r] = z2[row0 + ty * 8 + r];

    float best[8]; int bidx[8];
    #pragma unroll
    for (int r = 0; r < 8; ++r) { best[r] = FLT_MAX; bidx[r] = 0; }

    const int d4 = (tid & 7) * 4;  // d offset within chunk for staging
    const int pb = tid >> 3;       // row/col base for staging

    #pragma unroll 1
    for (int kc = 0; kc < KTOT / BN; ++kc) {
        const int k0 = kc * BN;
        float acc[8][8];
        #pragma unroll
        for (int r = 0; r < 8; ++r)
            #pragma unroll
            for (int c = 0; c < 8; ++c) acc[r][c] = 0.0f;

        #pragma unroll 1
        for (int dc = 0; dc < DIM / BD; ++dc) {
            __syncthreads();
            #pragma unroll
            for (int i = 0; i < 4; ++i) {
                const int px = pb + i * 32;
                float4 av = *(const float4*)(z  + (size_t)(row0 + px) * DIM + dc * BD + d4);
                T.As[d4 + 0][px] = av.x; T.As[d4 + 1][px] = av.y;
                T.As[d4 + 2][px] = av.z; T.As[d4 + 3][px] = av.w;
                float4 bv = *(const float4*)(cb + (size_t)(k0  + px) * DIM + dc * BD + d4);
                T.Bs[d4 + 0][px] = bv.x; T.Bs[d4 + 1][px] = bv.y;
                T.Bs[d4 + 2][px] = bv.z; T.Bs[d4 + 3][px] = bv.w;
            }
            __syncthreads();
            #pragma unroll 4
            for (int dd = 0; dd < BD; ++dd) {
                float4 a0 = *(const float4*)&T.As[dd][ty * 8];
                float4 a1 = *(const float4*)&T.As[dd][ty * 8 + 4];
                float4 b0 = *(const float4*)&T.Bs[dd][tx * 8];
                float4 b1 = *(const float4*)&T.Bs[dd][tx * 8 + 4];
                float a[8] = {a0.x, a0.y, a0.z, a0.w, a1.x, a1.y, a1.z, a1.w};
                float b[8] = {b0.x, b0.y, b0.z, b0.w, b1.x, b1.y, b1.z, b1.w};
                #pragma unroll
                for (int r = 0; r < 8; ++r)
                    #pragma unroll
                    for (int c = 0; c < 8; ++c)
                        acc[r][c] = fmaf(a[r], b[c], acc[r][c]);
            }
        }
        // fold this k-chunk into running argmin.
        // dist replicates ref rounding: (z2 + e2[k]) - 2*ze  (2*ze exact)
        float4 e0 = *(const float4*)(e2 + k0 + tx * 8);
        float4 e1 = *(const float4*)(e2 + k0 + tx * 8 + 4);
        float e2v[8] = {e0.x, e0.y, e0.z, e0.w, e1.x, e1.y, e1.z, e1.w};
        #pragma unroll
        for (int r = 0; r < 8; ++r) {
            #pragma unroll
            for (int c = 0; c < 8; ++c) {
                float dist = (z2r[r] + e2v[c]) - 2.0f * acc[r][c];
                // k strictly increases within a thread -> strict < keeps
                // earliest index on exact ties (matches np.argmin).
                if (dist < best[r]) { best[r] = dist; bidx[r] = k0 + tx * 8 + c; }
            }
        }
    }

    // cross-thread (k-direction) reduction, tie -> smaller index
    __syncthreads();
    #pragma unroll
    for (int r = 0; r < 8; ++r) {
        R.d[ty * 8 + r][tx] = best[r];
        R.i[ty * 8 + r][tx] = bidx[r];
    }
    __syncthreads();
    if (tid < BM) {
        float bd = R.d[tid][0]; int bi = R.i[tid][0];
        #pragma unroll
        for (int t = 1; t < 16; ++t) {
            float dc_ = R.d[tid][t]; int ic = R.i[tid][t];
            if (dc_ < bd || (dc_ == bd && ic < bi)) { bd = dc_; bi = ic; }
        }
        kwin[tid] = bi;
        out[OUT_IDX_OFF + row0 + tid] = (float)bi;
        atomicAdd(&hist[bi], 1u);
    }
    __syncthreads();

    // epilogue: z_q_st = z + (z_q - z) (ref rounding) + loss partial
    float lacc = 0.0f;
    #pragma unroll 4
    for (int i = 0; i < 32; ++i) {
        const int flat4 = tid + i * 256;
        const int row = flat4 >> 6;            // wave-uniform
        const int dj = (flat4 & 63) * 4;
        const size_t zoff = (size_t)(row0 + row) * DIM + dj;
        float4 zv = *(const float4*)(z + zoff);
        float4 ev = *(const float4*)(cb + (size_t)kwin[row] * DIM + dj);
        float dx = ev.x - zv.x, dy = ev.y - zv.y, dz = ev.z - zv.z, dw = ev.w - zv.w;
        float4 o;
        o.x = zv.x + dx; o.y = zv.y + dy; o.z = zv.z + dz; o.w = zv.w + dw;
        *(float4*)(out + zoff) = o;
        lacc += dx * dx + dy * dy + dz * dz + dw * dw;
    }
    #pragma unroll
    for (int off = 32; off > 0; off >>= 1) lacc += __shfl_down(lacc, off, 64);
    const int lane = tid & 63, wid = tid >> 6;
    if (lane == 0) wred[wid] = lacc;
    __syncthreads();
    if (tid == 0) atomicAdd(loss_sum, wred[0] + wred[1] + wred[2] + wred[3]);
}

// ---------------- finalize: losses + perplexity -----------------------------
__global__ __launch_bounds__(1024) void vq_finalize(
    const unsigned int* __restrict__ hist, const float* __restrict__ loss_sum,
    float* __restrict__ out)
{
    __shared__ float sred[16];
    __shared__ float totalsh;
    const int tid = threadIdx.x;
    const float c = (float)hist[tid];

    float t = c;
    #pragma unroll
    for (int off = 32; off > 0; off >>= 1) t += __shfl_down(t, off, 64);
    if ((tid & 63) == 0) sred[tid >> 6] = t;
    __syncthreads();
    if (tid == 0) {
        float s = 0.0f;
        for (int i = 0; i < 16; ++i) s += sred[i];
        totalsh = s;
    }
    __syncthreads();
    const float total = totalsh;
    const float prob = c / (total + EPS_);
    float term = prob * logf(prob + EPS_);
    __syncthreads();   // all phase-1 reads of sred done
    #pragma unroll
    for (int off = 32; off > 0; off >>= 1) term += __shfl_down(term, off, 64);
    if ((tid & 63) == 0) sred[tid >> 6] = term;
    __syncthreads();
    if (tid == 0) {
        float s = 0.0f;
        for (int i = 0; i < 16; ++i) s += sred[i];
        const float perp = expf(-s);
        const float S = *loss_sum;
        const float mean = S / (float)(P_TOT * DIM);   // == both losses
        out[OUT_LOSS_OFF + 0] = mean;                  // commitment_loss
        out[OUT_LOSS_OFF + 1] = mean;                  // codebook_loss
        out[OUT_LOSS_OFF + 2] = mean + BETA_ * mean;   // cluster_loss
        out[OUT_LOSS_OFF + 3] = perp;                  // perplexity
    }
}

extern "C" void kernel_launch(void* const* d_in, const int* in_sizes, int n_in,
                              void* d_out, int out_size, void* d_ws, size_t ws_size,
                              hipStream_t stream) {
    const float* z  = (const float*)d_in[0];
    const float* cb = (const float*)d_in[1];
    float* out = (float*)d_out;

    // ws layout: z2[P] | e2[K] | hist[K] (u32) | loss_sum (f32)  (~270 KiB)
    float* z2 = (float*)d_ws;
    float* e2 = z2 + P_TOT;
    unsigned int* hist = (unsigned int*)(e2 + KTOT);
    float* loss_sum = (float*)(hist + KTOT);

    vq_prep<<<KTOT, 64, 0, stream>>>(cb, e2, hist, loss_sum);
    vq_z2<<<P_TOT / 4, 256, 0, stream>>>(z, z2);
    vq_argmin<<<P_TOT / BM, 256, 0, stream>>>(z, cb, z2, e2, hist, loss_sum, out);
    vq_finalize<<<1, 1024, 0, stream>>>(hist, loss_sum, out);
}